// Round 1
// 1871.643 us; speedup vs baseline: 1.0270x; 1.0270x over previous
//
#include <hip/hip_runtime.h>
#include <stdint.h>

// TinyTransformer MI355X pipeline:
//   k_transpose (qkv_w, fc_w -> bf16 B^T) ; k_embed (gather->bf16)
//   k_gemm<1>  h @ qkv_wT + b -> Q,K (row-major bf16), V transposed [B][D][S]
//   k_attn     flash-style causal attention, bf16 MFMA, online softmax
//   k_gemm256  attn_out @ fc_wT + fc_b -> fp32 logits
//              (256x256 tile, 8 waves, dbuf LDS, counted vmcnt(8) pipeline,
//               raw s_barrier, setprio around MFMA, XCD supertile swizzle)

typedef unsigned short u16;
typedef __bf16 bf16x8 __attribute__((ext_vector_type(8)));
typedef float  f32x4  __attribute__((ext_vector_type(4)));

#define MFMA_BF16(a,b,c) __builtin_amdgcn_mfma_f32_16x16x32_bf16((a),(b),(c),0,0,0)

#define NB   4
#define NS   2048
#define ND   512
#define NV   32000

__device__ __forceinline__ u16 f2bf(float f) {            // RNE fp32 -> bf16 bits
  union { float f; uint32_t u; } v; v.f = f;
  uint32_t r = v.u + 0x7FFFu + ((v.u >> 16) & 1u);
  return (u16)(r >> 16);
}

__device__ __forceinline__ void gl2lds16(const void* g, void* l) {
  // async global->LDS, 16B/lane; LDS dest must be wave-uniform base + lane*16
  __builtin_amdgcn_global_load_lds(
      (__attribute__((address_space(1))) void*)(uintptr_t)g,
      (__attribute__((address_space(3))) void*)(uintptr_t)l, 16, 0, 0);
}

// ---------------- embedding gather + fp32->bf16 ----------------
__global__ void k_embed(const int* __restrict__ x, const float* __restrict__ E,
                        u16* __restrict__ H) {
  int t   = blockIdx.x * 256 + threadIdx.x;   // 8 elements per thread
  int row = t >> 6;                            // 64 threads per 512-wide row
  int col = (t & 63) << 3;
  int tok = x[row];
  const float4* src = (const float4*)(E + (size_t)tok * ND + col);
  float4 a = src[0], b = src[1];
  uint4 o;
  o.x = f2bf(a.x) | ((uint32_t)f2bf(a.y) << 16);
  o.y = f2bf(a.z) | ((uint32_t)f2bf(a.w) << 16);
  o.z = f2bf(b.x) | ((uint32_t)f2bf(b.y) << 16);
  o.w = f2bf(b.z) | ((uint32_t)f2bf(b.w) << 16);
  *(uint4*)(H + (size_t)t * 8) = o;
}

// ---------------- fp32 [K][N] -> bf16 [N][K] ----------------
__global__ void k_transpose(const float* __restrict__ W, u16* __restrict__ Wt,
                            int K, int N) {
  __shared__ u16 t[64][65];
  int n0 = blockIdx.x * 64, k0 = blockIdx.y * 64;
  for (int i = threadIdx.x; i < 4096; i += 256) {
    int r = i >> 6, c = i & 63;
    t[r][c] = f2bf(W[(size_t)(k0 + r) * N + n0 + c]);
  }
  __syncthreads();
  for (int i = threadIdx.x; i < 4096; i += 256) {
    int nr = i >> 6, kc = i & 63;
    Wt[(size_t)(n0 + nr) * K + k0 + kc] = t[kc][nr];
  }
}

// ---------------- 128x128 bf16 GEMM (kept for the QKV projection) ----------
// EPI==1: split into Q,K (bf16 [M][512]) and V transposed (bf16 [B][512][2048]) + bias
template <int EPI>
__global__ __launch_bounds__(256)
void k_gemm(const u16* __restrict__ A, const u16* __restrict__ Bt,
            const float* __restrict__ bias, float* __restrict__ C,
            u16* __restrict__ Qo, u16* __restrict__ Ko, u16* __restrict__ Vto,
            int N) {
  __shared__ u16 As[128 * 64];   // 16 KB, XOR-swizzled 16B chunks
  __shared__ u16 Bs[128 * 64];
  const int tid = threadIdx.x;
  const int w = tid >> 6, lane = tid & 63, quad = lane >> 4, l16 = lane & 15;
  const int wr = w >> 1, wc = w & 1;
  const int m0 = blockIdx.y * 128, n0 = blockIdx.x * 128;
  f32x4 acc[4][4] = {};

  for (int kt = 0; kt < 8; ++kt) {
    const int k0 = kt * 64;
#pragma unroll
    for (int it = 0; it < 4; ++it) {          // A tile: 1024 chunks of 16B
      int idx = it * 256 + tid;
      int r = idx >> 3, p = idx & 7;          // LDS pos p holds global chunk p^(r&7)
      gl2lds16(A + (size_t)(m0 + r) * 512 + k0 + ((p ^ (r & 7)) << 3), As + idx * 8);
    }
#pragma unroll
    for (int it = 0; it < 4; ++it) {
      int idx = it * 256 + tid;
      int r = idx >> 3, p = idx & 7;
      gl2lds16(Bt + (size_t)(n0 + r) * 512 + k0 + ((p ^ (r & 7)) << 3), Bs + idx * 8);
    }
    __syncthreads();
#pragma unroll
    for (int ks = 0; ks < 2; ++ks) {
      bf16x8 af[4], bf[4];
      const int cl = ks * 4 + quad;           // global chunk wanted
#pragma unroll
      for (int mt = 0; mt < 4; ++mt) {
        int r = wr * 64 + mt * 16 + l16;
        af[mt] = *(const bf16x8*)(As + ((r * 8 + (cl ^ (r & 7))) << 3));
      }
#pragma unroll
      for (int nt = 0; nt < 4; ++nt) {
        int r = wc * 64 + nt * 16 + l16;
        bf[nt] = *(const bf16x8*)(Bs + ((r * 8 + (cl ^ (r & 7))) << 3));
      }
#pragma unroll
      for (int mt = 0; mt < 4; ++mt)
#pragma unroll
        for (int nt = 0; nt < 4; ++nt)
          acc[mt][nt] = MFMA_BF16(af[mt], bf[nt], acc[mt][nt]);
    }
    __syncthreads();
  }

  // epilogue: C layout col=lane&15, row=quad*4+reg
#pragma unroll
  for (int nt = 0; nt < 4; ++nt) {
    const int n = n0 + wc * 64 + nt * 16 + l16;
    const float bv = bias[n];
#pragma unroll
    for (int mt = 0; mt < 4; ++mt) {
      const int mb = m0 + wr * 64 + mt * 16 + quad * 4;
#pragma unroll
      for (int j = 0; j < 4; ++j) {
        float v = acc[mt][nt][j] + bv;
        if (EPI == 0) {
          C[(size_t)(mb + j) * N + n] = v;
        } else {
          u16 hb = f2bf(v);
          int m = mb + j;
          if (n < 512)        Qo[(size_t)m * 512 + n] = hb;
          else if (n < 1024)  Ko[(size_t)m * 512 + (n - 512)] = hb;
          else {
            int d = n - 1024, bb = m >> 11, ss = m & 2047;  // S=2048
            Vto[((size_t)(bb * 512 + d)) * 2048 + ss] = hb;
          }
        }
      }
    }
  }
}

// ---------------- 256x256 bf16 GEMM with counted-vmcnt pipeline --------------
// A [M][512] bf16 row-major, Bt [N][512] bf16 row-major (B^T), C fp32 [M][N].
// 512 threads = 8 waves (2 M x 4 N), per-wave 128x64 output, acc f32x4[8][4].
// LDS: 2 x (A 256x64 + B 256x64) = 128 KB double buffer, XOR-swizzled chunks.
// Main loop: STAGE(t+1) -> s_waitcnt vmcnt(8) -> s_barrier -> MFMA(t) -> s_barrier.
// Loads for t+1 stay in flight across the barrier (no vmcnt(0) drain until t=7).
__device__ __forceinline__ void stage_tile256(const u16* __restrict__ A,
                                              const u16* __restrict__ Bt,
                                              int m0, int n0, int k0,
                                              u16* As, u16* Bs, int tid) {
#pragma unroll
  for (int it = 0; it < 4; ++it) {             // A: 2048 chunks of 16B
    int idx = it * 512 + tid;
    int r = idx >> 3, p = idx & 7;             // LDS slot p holds global chunk p^(r&7)
    gl2lds16(A + (size_t)(m0 + r) * 512 + k0 + ((p ^ (r & 7)) << 3), As + idx * 8);
  }
#pragma unroll
  for (int it = 0; it < 4; ++it) {             // B: 2048 chunks of 16B
    int idx = it * 512 + tid;
    int r = idx >> 3, p = idx & 7;
    gl2lds16(Bt + (size_t)(n0 + r) * 512 + k0 + ((p ^ (r & 7)) << 3), Bs + idx * 8);
  }
}

__global__ __launch_bounds__(512, 2)
void k_gemm256(const u16* __restrict__ A, const u16* __restrict__ Bt,
               const float* __restrict__ bias, float* __restrict__ C, int N) {
  __shared__ u16 As[2][256 * 64];              // 64 KB
  __shared__ u16 Bs[2][256 * 64];              // 64 KB
  const int tid = threadIdx.x;
  const int w = tid >> 6, lane = tid & 63, quad = lane >> 4, l16 = lane & 15;
  const int wr = w >> 2, wc = w & 3;

  // bijective supertile swizzle: XCD chunks of 500 blocks; supertile = 8m x 5n
  // blocks (A panels 2.1 MB + B panels 1.3 MB ~ one XCD L2).
  const int bid = blockIdx.x;                  // 0..3999
  const int l  = (bid & 7) * 500 + (bid >> 3);
  const int st = l / 40, si = l % 40;          // 100 supertiles of 40 blocks
  const int m0 = ((st & 3) * 8 + (si & 7)) * 256;   // 4 x 8 = 32 m-blocks
  const int n0 = ((st >> 2) * 5 + (si >> 3)) * 256; // 25 x 5 = 125 n-blocks

  f32x4 acc[8][4] = {};

  stage_tile256(A, Bt, m0, n0, 0, As[0], Bs[0], tid);
  int cur = 0;
  for (int t = 0; t < 8; ++t) {
    if (t < 7) {
      // buf[cur^1] reads (tile t-1) finished at previous end-barrier -> safe.
      stage_tile256(A, Bt, m0, n0, (t + 1) * 64, As[cur ^ 1], Bs[cur ^ 1], tid);
      // newest 8 loads are tile t+1's; waiting to 8 => tile t fully landed.
      asm volatile("s_waitcnt vmcnt(8)" ::: "memory");
    } else {
      asm volatile("s_waitcnt vmcnt(0)" ::: "memory");
    }
    __builtin_amdgcn_s_barrier();              // everyone's tile-t DMA visible
    __builtin_amdgcn_sched_barrier(0);

    const u16* Ab = As[cur];
    const u16* Bb = Bs[cur];
    bf16x8 bfr[4][2];
#pragma unroll
    for (int nt = 0; nt < 4; ++nt)
#pragma unroll
      for (int kk = 0; kk < 2; ++kk) {
        int r = wc * 64 + nt * 16 + l16;
        int cl = kk * 4 + quad;
        bfr[nt][kk] = *(const bf16x8*)(Bb + ((r * 8 + (cl ^ (r & 7))) << 3));
      }
#pragma unroll
    for (int qd = 0; qd < 4; ++qd) {           // 4 phases: 2 m-frags x 4 n x 2 kk
      bf16x8 af[2][2];
#pragma unroll
      for (int mi = 0; mi < 2; ++mi)
#pragma unroll
        for (int kk = 0; kk < 2; ++kk) {
          int r = wr * 128 + (qd * 2 + mi) * 16 + l16;
          int cl = kk * 4 + quad;
          af[mi][kk] = *(const bf16x8*)(Ab + ((r * 8 + (cl ^ (r & 7))) << 3));
        }
      __builtin_amdgcn_s_setprio(1);
#pragma unroll
      for (int mi = 0; mi < 2; ++mi)
#pragma unroll
        for (int nt = 0; nt < 4; ++nt)
#pragma unroll
          for (int kk = 0; kk < 2; ++kk)
            acc[qd * 2 + mi][nt] =
                MFMA_BF16(af[mi][kk], bfr[nt][kk], acc[qd * 2 + mi][nt]);
      __builtin_amdgcn_s_setprio(0);
    }
    asm volatile("" ::: "memory");
    __builtin_amdgcn_s_barrier();              // all reads of buf[cur] done
    __builtin_amdgcn_sched_barrier(0);
    cur ^= 1;
  }

  // epilogue: C layout col=lane&15, row=quad*4+reg
#pragma unroll
  for (int nt = 0; nt < 4; ++nt) {
    const int n = n0 + wc * 64 + nt * 16 + l16;
    const float bv = bias[n];
#pragma unroll
    for (int mt = 0; mt < 8; ++mt) {
      const int mb = m0 + wr * 128 + mt * 16 + quad * 4;
#pragma unroll
      for (int j = 0; j < 4; ++j)
        C[(size_t)(mb + j) * N + n] = acc[mt][nt][j] + bv;
    }
  }
}

// ---------------- flash-style causal attention ----------------
// grid (32 q-tiles, 4 batches), 256 threads. Q,K bf16 [B*S][512]; V transposed [B][512][2048].
// LDS: 64KB K-tile; first ~10KB reused (post-barrier) for P (C->A layout round-trip) + alpha/l.
__global__ __launch_bounds__(256, 2)
void k_attn(const u16* __restrict__ Q, const u16* __restrict__ Kk,
            const u16* __restrict__ Vt, u16* __restrict__ O) {
  __shared__ u16 lds[64 * 512];                         // exactly 64 KB
  u16 (*Pl)[72] = (u16(*)[72])lds;                      // 64x72 bf16, aliases K rows 0..8
  float* alpha_sh = (float*)(lds + 64 * 72);            // byte 9216
  float* l_sh     = alpha_sh + 64;

  const int b = blockIdx.y, qt = blockIdx.x;
  const int tid = threadIdx.x;
  const int w = tid >> 6, lane = tid & 63, quad = lane >> 4, l16 = lane & 15;
  const int q0 = qt * 64;
  const u16* Qb = Q  + (size_t)b * NS * ND;
  const u16* Kb = Kk + (size_t)b * NS * ND;
  const u16* Vb = Vt + (size_t)b * ND * NS;
  const u16* qrow = Qb + (size_t)(q0 + w * 16 + l16) * ND + quad * 8;  // A-frag base

  f32x4 oacc[4][8] = {};                  // 64 q-rows x 128-d slice (w*128)
  float m_i[4] = {-1e30f, -1e30f, -1e30f, -1e30f};
  float l_i[4] = {0.f, 0.f, 0.f, 0.f};
  const float scale = 0.044194173824159216f;  // 1/sqrt(512)

  for (int kt = 0; kt <= qt; ++kt) {
    // stage K tile 64x512 bf16 (swizzled chunks)
#pragma unroll
    for (int it = 0; it < 16; ++it) {
      int idx = it * 256 + tid;
      int r = idx >> 6, p = idx & 63;
      gl2lds16(Kb + (size_t)(kt * 64 + r) * ND + ((p ^ (r & 7)) << 3), lds + idx * 8);
    }
    __syncthreads();                                   // B1 (drains vmcnt)

    // scores: wave w computes q-rows [w*16, w*16+16) x 64 keys
    f32x4 s[4] = {};
#pragma unroll
    for (int ks = 0; ks < 16; ++ks) {
      bf16x8 aq = *(const bf16x8*)(qrow + ks * 32);
#pragma unroll
      for (int nt = 0; nt < 4; ++nt) {
        int r = nt * 16 + l16;
        bf16x8 bk = *(const bf16x8*)(lds + ((r * 64 + ((ks * 4 + quad) ^ (r & 7))) << 3));
        s[nt] = MFMA_BF16(aq, bk, s[nt]);
      }
    }

    const bool diag = (kt == qt);
#pragma unroll
    for (int nt = 0; nt < 4; ++nt)
#pragma unroll
      for (int j = 0; j < 4; ++j) {
        float v = s[nt][j] * scale;
        if (diag && (nt * 16 + l16) > (w * 16 + quad * 4 + j)) v = -1e30f;
        s[nt][j] = v;
      }
    float rmax[4], alj[4], rsum[4];
#pragma unroll
    for (int j = 0; j < 4; ++j)
      rmax[j] = fmaxf(fmaxf(s[0][j], s[1][j]), fmaxf(s[2][j], s[3][j]));
#pragma unroll
    for (int off = 8; off >= 1; off >>= 1)
#pragma unroll
      for (int j = 0; j < 4; ++j)
        rmax[j] = fmaxf(rmax[j], __shfl_xor(rmax[j], off));
#pragma unroll
    for (int j = 0; j < 4; ++j) {
      float mnew = fmaxf(m_i[j], rmax[j]);
      alj[j] = __expf(m_i[j] - mnew);
      m_i[j] = mnew;
    }
#pragma unroll
    for (int nt = 0; nt < 4; ++nt)
#pragma unroll
      for (int j = 0; j < 4; ++j)
        s[nt][j] = __expf(s[nt][j] - m_i[j]);
#pragma unroll
    for (int j = 0; j < 4; ++j)
      rsum[j] = (s[0][j] + s[1][j]) + (s[2][j] + s[3][j]);
#pragma unroll
    for (int off = 8; off >= 1; off >>= 1)
#pragma unroll
      for (int j = 0; j < 4; ++j)
        rsum[j] += __shfl_xor(rsum[j], off);
#pragma unroll
    for (int j = 0; j < 4; ++j)
      l_i[j] = alj[j] * l_i[j] + rsum[j];

    __syncthreads();                                   // B2: all ldsK reads done

    // P (bf16) + alpha into the aliased low region
#pragma unroll
    for (int nt = 0; nt < 4; ++nt)
#pragma unroll
      for (int j = 0; j < 4; ++j)
        Pl[w * 16 + quad * 4 + j][nt * 16 + l16] = f2bf(s[nt][j]);
    if (l16 == 0) {
#pragma unroll
      for (int j = 0; j < 4; ++j) alpha_sh[w * 16 + quad * 4 + j] = alj[j];
    }
    __syncthreads();                                   // B3

    // rescale O accumulator by per-row alpha (rows owned by other waves too)
#pragma unroll
    for (int mt = 0; mt < 4; ++mt)
#pragma unroll
      for (int j = 0; j < 4; ++j) {
        float al = alpha_sh[mt * 16 + quad * 4 + j];
#pragma unroll
        for (int nt = 0; nt < 8; ++nt) oacc[mt][nt][j] *= al;
      }

    // PV: A = P[64x64] from LDS, B = V (via transposed Vt, contiguous along keys)
#pragma unroll
    for (int k2 = 0; k2 < 2; ++k2) {
      bf16x8 af[4];
#pragma unroll
      for (int mt = 0; mt < 4; ++mt)
        af[mt] = *(const bf16x8*)(&Pl[mt * 16 + l16][k2 * 32 + quad * 8]);
#pragma unroll
      for (int nt = 0; nt < 8; ++nt) {
        bf16x8 bv = *(const bf16x8*)(Vb + (size_t)(w * 128 + nt * 16 + l16) * NS +
                                     kt * 64 + k2 * 32 + quad * 8);
#pragma unroll
        for (int mt = 0; mt < 4; ++mt)
          oacc[mt][nt] = MFMA_BF16(af[mt], bv, oacc[mt][nt]);
      }
    }
    __syncthreads();                                   // B4: P reads done before restage
  }

  if (l16 == 0) {
#pragma unroll
    for (int j = 0; j < 4; ++j) l_sh[w * 16 + quad * 4 + j] = l_i[j];
  }
  __syncthreads();
#pragma unroll
  for (int mt = 0; mt < 4; ++mt)
#pragma unroll
    for (int j = 0; j < 4; ++j) {
      float inv = 1.0f / l_sh[mt * 16 + quad * 4 + j];
      int m = q0 + mt * 16 + quad * 4 + j;
#pragma unroll
      for (int nt = 0; nt < 8; ++nt)
        O[((size_t)b * NS + m) * ND + w * 128 + nt * 16 + l16] =
            f2bf(oacc[mt][nt][j] * inv);
    }
}

// ---------------- launcher ----------------
extern "C" void kernel_launch(void* const* d_in, const int* in_sizes, int n_in,
                              void* d_out, int out_size, void* d_ws, size_t ws_size,
                              hipStream_t stream) {
  (void)in_sizes; (void)n_in; (void)out_size; (void)ws_size;
  const int*   x      = (const int*)d_in[0];
  const float* embedW = (const float*)d_in[1];
  const float* qkv_w  = (const float*)d_in[2];
  const float* qkv_b  = (const float*)d_in[3];
  const float* fc_w   = (const float*)d_in[4];
  const float* fc_b   = (const float*)d_in[5];
  float* out = (float*)d_out;
  char*  ws  = (char*)d_ws;

  size_t off = 0;
  auto alloc = [&](size_t bytes) { void* p = ws + off; off += (bytes + 255) & ~(size_t)255; return p; };
  u16* Hb    = (u16*)alloc((size_t)NB * NS * ND * 2);        // 8 MB  bf16 embeddings
  u16* qkvwT = (u16*)alloc((size_t)3 * ND * ND * 2);         // 1.5 MB
  u16* fcwT  = (u16*)alloc((size_t)NV * ND * 2);             // 32.8 MB
  u16* Qp    = (u16*)alloc((size_t)NB * NS * ND * 2);        // 8 MB
  u16* Kp    = (u16*)alloc((size_t)NB * NS * ND * 2);        // 8 MB
  u16* Vtp   = (u16*)alloc((size_t)NB * ND * NS * 2);        // 8 MB (transposed)
  u16* Ob    = (u16*)alloc((size_t)NB * NS * ND * 2);        // 8 MB attention out

  k_transpose<<<dim3(1536 / 64, 512 / 64), 256, 0, stream>>>(qkv_w, qkvwT, 512, 1536);
  k_transpose<<<dim3(NV / 64, 512 / 64), 256, 0, stream>>>(fc_w, fcwT, 512, NV);
  k_embed<<<(NB * NS * 64) / 256, 256, 0, stream>>>(x, embedW, Hb);
  k_gemm<1><<<dim3(1536 / 128, (NB * NS) / 128), 256, 0, stream>>>(
      Hb, qkvwT, qkv_b, nullptr, Qp, Kp, Vtp, 1536);
  k_attn<<<dim3(NS / 64, NB), 256, 0, stream>>>(Qp, Kp, Vtp, Ob);
  k_gemm256<<<dim3((NV / 256) * ((NB * NS) / 256)), 512, 0, stream>>>(
      Ob, fcwT, fc_b, out, NV);
}